// Round 7
// baseline (4611.816 us; speedup 1.0000x reference)
//
#include <hip/hip_runtime.h>
#include <math.h>

#define LL 256
#define BB 256
#define HH 256
#define CC 16
#define YY 32
#define HC (HH*CC)     // 4096
#define NSTEP (LL-1)   // 255
#define NBG 32         // batch groups total (2 per block)
#define BGB 8          // batches per group
#define NSIB 16        // sibling blocks per bg (= NHC)
#define COLS 256       // W2 cols per block (16 h's x 16 c)
#define TPB 1024
#define NJS 8          // phase-B j-split slices (FROZEN: bit-exact chain order)

typedef __attribute__((ext_vector_type(2))) float f32x2;

// fast tanh — IDENTICAL to the passing baseline (bit-exact frozen).
__device__ __forceinline__ float fast_tanh(float x) {
    float e = __expf(2.0f * x);
    return 1.0f - 2.0f / (e + 1.0f);
}

// device-coherent access (bypasses non-coherent per-XCD L2s) — proven r0-r6.
__device__ __forceinline__ float2 ld_coh2(const float* p) {
    union { unsigned long long u; float2 f; } cv;
    cv.u = __hip_atomic_load((const unsigned long long*)p,
                             __ATOMIC_RELAXED, __HIP_MEMORY_SCOPE_AGENT);
    return cv.f;
}
__device__ __forceinline__ void st_coh(float* p, float v) {
    __hip_atomic_store(p, v, __ATOMIC_RELAXED, __HIP_MEMORY_SCOPE_AGENT);
}

// split barrier: arrive (all stores drained by __syncthreads' vmcnt(0)) and
// wait (poll then barrier). Per-pipeline monotonic counter, r6-proven invariant.
__device__ __forceinline__ void bg_arrive(unsigned* cnt) {
    __syncthreads();
    if (threadIdx.x == 0)
        __hip_atomic_fetch_add(cnt, 1u, __ATOMIC_RELAXED, __HIP_MEMORY_SCOPE_AGENT);
}
__device__ __forceinline__ void bg_wait(unsigned* cnt, unsigned target) {
    if (threadIdx.x == 0)
        while (__hip_atomic_load(cnt, __ATOMIC_RELAXED, __HIP_MEMORY_SCOPE_AGENT) < target)
            __builtin_amdgcn_s_sleep(1);
    __syncthreads();
}

// ---------------------------------------------------------------------------
// persistent scan: 256 blocks = 16 bg-pairs x 16 hc, 1024 threads, 1 block/CU.
// Each block runs TWO independent batch-group pipelines (A,B) interleaved so
// every cross-block barrier wait overlaps the other pipeline's compute.
// Block slice: 16 h's (h0..h0+15) = 256 W2 cols. NUMERICS BIT-IDENTICAL to
// r6/baseline: identical FMA chain element order everywhere.
// ---------------------------------------------------------------------------
__global__ void __launch_bounds__(TPB, 4)
k_scan(const float* __restrict__ us, const float* __restrict__ W1,
       const float* __restrict__ b1, const float* __restrict__ W2,
       const float* __restrict__ b2, float* __restrict__ zs,
       float* __restrict__ hidG, unsigned* __restrict__ barG) {
    // floats: psum 16384 | zA 2048 | zB 2048 | hid 2048 | dvsA 128 | dvsB 128
    //         b2s 256 | b1s 16  => 23056 floats = 90.1 KB (1 block/CU)
    __shared__ __align__(16) float smem[23056];
    float* psum = smem;                 // [8][8][256] (phase B/dz)
    float* pa   = smem;                 // alias [32][132] (phase A partials)
    float* zA   = smem + 16384;         // [8][256]
    float* zB   = zA + 2048;            // [8][256]
    float* hidL = zB + 2048;            // [8][256] (time-shared A then B)
    float* dvsA = hidL + 2048;          // [8][16]
    float* dvsB = dvsA + 128;           // [8][16]
    float* b2s  = dvsB + 128;           // [256]
    float* b1s  = b2s + 256;            // [16]

    const int bp  = blockIdx.x >> 4;                         // bg-pair 0..15
    const int hc  = (blockIdx.x & 7) * 2 + ((blockIdx.x >> 3) & 1); // XCD-aligned
    const int t   = threadIdx.x;
    const int b0A = (bp * 2) * BGB;
    const int b0B = (bp * 2 + 1) * BGB;
    const int h0  = hc * 16;
    const int n0  = h0 * CC;                                 // = hc*256

    // ---- one-time preload ----
    // phase-A decode: ah = h-local, ajc = 8-j chunk (0..31), half = batch half
    const int ah   = t & 15;
    const int ajc  = (t >> 4) & 31;
    const int half = t >> 9;
    float w1r[8];
    #pragma unroll
    for (int r = 0; r < 8; r++)
        w1r[r] = W1[(size_t)(ajc * 8 + r) * HH + h0 + ah];
    for (int i = t; i < COLS; i += TPB) b2s[i] = b2[n0 + i];
    if (t < 16) b1s[t] = b1[h0 + t];
    __syncthreads();

    unsigned* cntA = barG + (size_t)(bp * 2) * 64;           // 256-B lines
    unsigned* cntB = barG + (size_t)(bp * 2 + 1) * 64;

    // staging decode (8-B coherent loads)
    const int sb  = t >> 7;              // 0..7
    const int sj2 = (t & 127) << 1;      // 0,2,..,254
    // phase-B decode: jsp slice of 32 j's, col-pair cp
    const int jsp = t >> 7;              // 0..7
    const int cp  = (t & 127) << 1;      // 0..254
    // dz decode
    const int col = t & 255;
    const int bh  = (t >> 8) << 1;       // 0,2,4,6

    for (int k = 0; k < NSTEP; k++) {
        const size_t zk = (size_t)k * (BB * HH);

        #pragma unroll 1
        for (int pipe = 0; pipe < 2; pipe++) {
            unsigned* cnt = pipe ? cntB : cntA;
            float* z_loc  = pipe ? zB : zA;
            float* dvs    = pipe ? dvsB : dvsA;
            const int b0  = pipe ? b0B : b0A;

            // ---- wait for this pipeline's z[k] (dz of step k-1) ----
            if (k) bg_wait(cnt, 16u * (2u * (unsigned)k));

            // ---- stage z + dvs ----
            {
                float2 v = ld_coh2(&zs[zk + (size_t)(b0 + sb) * HH + sj2]);
                *(float2*)&z_loc[sb * HH + sj2] = v;
            }
            if (t < BGB * CC) {
                int b = t >> 4, c = t & 15;
                int kk = (k < 1) ? 1 : k;
                float v = 1.0f;          // c==0: ts diff == 1
                if (c > 0)
                    v = us[((size_t)kk * BB + b0 + b) * (CC - 1) + c - 1]
                      - us[((size_t)(kk - 1) * BB + b0 + b) * (CC - 1) + c - 1];
                dvs[b * CC + c] = v;
            }
            __syncthreads();

            // ---- phase A: partial hid[b][h0+ah] over 8 j's (W1 in regs) ----
            // chain per (b,h): identical 8-j chunks, 32 partials, same order.
            {
                float acc[4];
                #pragma unroll
                for (int i = 0; i < 4; i++) acc[i] = 0.f;
                #pragma unroll
                for (int r2 = 0; r2 < 2; r2++) {
                    #pragma unroll
                    for (int i = 0; i < 4; i++) {
                        float4 zv = *(const float4*)&z_loc[(half * 4 + i) * HH + ajc * 8 + r2 * 4];
                        acc[i] += zv.x * w1r[r2 * 4 + 0] + zv.y * w1r[r2 * 4 + 1]
                                + zv.z * w1r[r2 * 4 + 2] + zv.w * w1r[r2 * 4 + 3];
                    }
                }
                #pragma unroll
                for (int i = 0; i < 4; i++)
                    pa[ajc * 132 + (half * 4 + i) * 16 + ah] = acc[i];  // 132: pad, no conflict
            }
            __syncthreads();
            if (t < BGB * 16) {          // reduce 32 partials in order, relu, publish
                float s = b1s[t & 15];
                #pragma unroll
                for (int q = 0; q < 32; q++) s += pa[q * 132 + t];
                st_coh(&hidG[(size_t)(b0 + (t >> 4)) * HH + h0 + (t & 15)],
                       fmaxf(s, 0.f));
            }
            bg_arrive(cnt);              // slot 2k+1: hid slice published
        }

        #pragma unroll 1
        for (int pipe = 0; pipe < 2; pipe++) {
            unsigned* cnt = pipe ? cntB : cntA;
            float* z_loc  = pipe ? zB : zA;
            float* dvs    = pipe ? dvsB : dvsA;
            const int b0  = pipe ? b0B : b0A;

            // ---- wait: all 16 siblings published hid for this pipeline ----
            bg_wait(cnt, 16u * (2u * (unsigned)k + 1u));

            // ---- stage hid (natural layout, coherent 8B) ----
            {
                float2 v = ld_coh2(&hidG[(size_t)(b0 + sb) * HH + sj2]);
                *(float2*)&hidL[sb * HH + sj2] = v;
            }
            __syncthreads();

            // ---- phase B: hid(8x256) @ W2-slice(256x256) ----
            // chain per (b,col): 32-j slice, j-quads in order, x,y,z,w — frozen.
            {
                f32x2 acc[BGB];
                #pragma unroll
                for (int b = 0; b < BGB; b++) acc[b] = (f32x2){0.f, 0.f};
                const int jb = jsp * 32;
                const float* w2p = &W2[(size_t)jb * HC + n0 + cp];
                #pragma unroll 2
                for (int jq = 0; jq < 32; jq += 4) {
                    f32x2 w0 = *(const f32x2*)&w2p[(size_t)(jq + 0) * HC];
                    f32x2 w1 = *(const f32x2*)&w2p[(size_t)(jq + 1) * HC];
                    f32x2 w2v = *(const f32x2*)&w2p[(size_t)(jq + 2) * HC];
                    f32x2 w3 = *(const f32x2*)&w2p[(size_t)(jq + 3) * HC];
                    #pragma unroll
                    for (int b = 0; b < BGB; b++) {
                        float4 h4 = *(const float4*)&hidL[b * HH + jb + jq]; // bcast
                        acc[b] = h4.x * w0  + acc[b];
                        acc[b] = h4.y * w1  + acc[b];
                        acc[b] = h4.z * w2v + acc[b];
                        acc[b] = h4.w * w3  + acc[b];
                    }
                }
                #pragma unroll
                for (int b = 0; b < BGB; b++)
                    *(f32x2*)&psum[((jsp * BGB + b) << 8) + cp] = acc[b];
            }
            __syncthreads();

            // ---- dz + z update: g = b2 + psum slices s=0..7 (frozen order) ----
            {
                #pragma unroll
                for (int q = 0; q < 2; q++) {
                    int b = bh + q;
                    float g = b2s[col];
                    #pragma unroll
                    for (int s = 0; s < NJS; s++)
                        g += psum[((s * BGB + b) << 8) + col];   // stride-1
                    float v = fast_tanh(g) * dvs[b * CC + (col & 15)];
                    v += __shfl_xor(v, 1);
                    v += __shfl_xor(v, 2);
                    v += __shfl_xor(v, 4);
                    v += __shfl_xor(v, 8);
                    if ((col & 15) == 0) {
                        int hl = col >> 4;
                        st_coh(&zs[zk + (size_t)(BB * HH) + (size_t)(b0 + b) * HH + h0 + hl],
                               z_loc[b * HH + h0 + hl] + v);     // dt == 1
                    }
                }
            }
            bg_arrive(cnt);              // slot 2k+2: z[k+1] slice published
        }
    }
}

// ---------------------------------------------------------------------------
// out = tanh(z_seq @ dW1 + db1) @ dW2 + db2   — UNCHANGED from baseline.
// ---------------------------------------------------------------------------
__global__ void k_out(const float* __restrict__ zseq, const float* __restrict__ dW1,
                      const float* __restrict__ db1, const float* __restrict__ dW2,
                      const float* __restrict__ db2, float* __restrict__ out) {
    __shared__ float zt[16][HH];       // 16 KB
    __shared__ float act[16][2 * HH];  // 32 KB
    int r0 = blockIdx.x * 16;
    int t  = threadIdx.x;
    {
        const float4* src = (const float4*)(zseq + (size_t)r0 * HH);
        float4* dst = (float4*)&zt[0][0];
        for (int i = t; i < 1024; i += 256) dst[i] = src[i];
    }
    __syncthreads();
    {   // phase 1: act = tanh(z @ dW1 + db1), 512 cols
        int c0  = (t & 127) * 4;
        int rr0 = (t >> 7) * 8;
        float a[8][4];
        #pragma unroll
        for (int i = 0; i < 8; i++)
            #pragma unroll
            for (int q = 0; q < 4; q++) a[i][q] = 0.f;
        for (int j = 0; j < HH; j++) {
            float4 w = *(const float4*)&dW1[(size_t)j * 2 * HH + c0];
            #pragma unroll
            for (int i = 0; i < 8; i++) {
                float zv = zt[rr0 + i][j];
                a[i][0] += zv * w.x; a[i][1] += zv * w.y;
                a[i][2] += zv * w.z; a[i][3] += zv * w.w;
            }
        }
        float4 bias = *(const float4*)&db1[c0];
        #pragma unroll
        for (int i = 0; i < 8; i++) {
            act[rr0 + i][c0 + 0] = fast_tanh(a[i][0] + bias.x);
            act[rr0 + i][c0 + 1] = fast_tanh(a[i][1] + bias.y);
            act[rr0 + i][c0 + 2] = fast_tanh(a[i][2] + bias.z);
            act[rr0 + i][c0 + 3] = fast_tanh(a[i][3] + bias.w);
        }
    }
    __syncthreads();
    {   // phase 2: out = act @ dW2 + db2
        int rl = t >> 4;
        int y2 = t & 15;
        float o0 = 0.f, o1 = 0.f;
        #pragma unroll 4
        for (int j = 0; j < 2 * HH; j++) {
            float av = act[rl][j];
            float2 w = *(const float2*)&dW2[(size_t)j * YY + y2 * 2];
            o0 += av * w.x; o1 += av * w.y;
        }
        float2 bias = *(const float2*)&db2[y2 * 2];
        out[(size_t)(r0 + rl) * YY + y2 * 2]     = o0 + bias.x;
        out[(size_t)(r0 + rl) * YY + y2 * 2 + 1] = o1 + bias.y;
    }
}

// ---------------------------------------------------------------------------
extern "C" void kernel_launch(void* const* d_in, const int* in_sizes, int n_in,
                              void* d_out, int out_size, void* d_ws, size_t ws_size,
                              hipStream_t stream) {
    const float* us  = (const float*)d_in[1];
    const float* h0  = (const float*)d_in[2];
    const float* W1  = (const float*)d_in[3];
    const float* b1  = (const float*)d_in[4];
    const float* W2  = (const float*)d_in[5];
    const float* b2  = (const float*)d_in[6];
    const float* dW1 = (const float*)d_in[7];
    const float* db1 = (const float*)d_in[8];
    const float* dW2 = (const float*)d_in[9];
    const float* db2 = (const float*)d_in[10];
    float* out = (float*)d_out;

    float* zs   = (float*)d_ws;                          // L*B*H = 64 MB
    float* hidG = zs + (size_t)LL * BB * HH;             // B*H   = 256 KB
    unsigned* barG = (unsigned*)(hidG + (size_t)BB * HH); // 32 x 256 B = 8 KB

    hipMemcpyAsync(zs, h0, (size_t)BB * HH * sizeof(float),
                   hipMemcpyDeviceToDevice, stream);
    hipMemsetAsync(barG, 0, NBG * 64 * sizeof(unsigned), stream);

    k_scan<<<256, TPB, 0, stream>>>(us, W1, b1, W2, b2, zs, hidG, barG);
    k_out<<<LL * BB / 16, 256, 0, stream>>>(zs, dW1, db1, dW2, db2, out);
}